// Round 13
// baseline (289.772 us; speedup 1.0000x reference)
//
#include <hip/hip_runtime.h>
#include <math.h>

#define ROWN 10000
#define COLN 4096
#define DIM 16
#define EN 1000000
#define RECLEN 160   // floats per column record (640 B = 40 float4)
// record float4 layout: [0]=(1,t,t^2/2,t^3/6) [1..4]=A diag [5..34]=B cross(120)
//                       [35..38]=h [39]=(g0, gamma_col, 0, 0)
#define NB 64        // sort chunks
#define CHUNK 15625  // EN / NB exact
#define PK_CAP 1261568   // >= EN + COLN*63 = 1,258,048; multiple of 64

// fused_k block ranges: hist first (critical path), then precompute, then repack
#define HIST_BLKS 64
#define PRE_BLKS 4096
#define RPK_BLKS 157     // ceil(10000*64 / (256*16))

#define EDGE_BLKS 1024   // ~4 slots/thread; VGPR ~112 -> 4 waves/SIMD fits

struct Ctrl { double acc; int blkcnt; int pk_len; };

typedef _Float16 halfv8 __attribute__((ext_vector_type(8)));

__device__ __forceinline__ halfv8 splat8(_Float16 x) {
    halfv8 v;
    #pragma unroll
    for (int j = 0; j < 8; ++j) v[j] = x;
    return v;
}
union F4H8 { float4 f; halfv8 h; };

// compile-time (d,dp) pair table for the 120 cross terms
struct PairTab { int d[120]; int p[120]; };
__host__ __device__ constexpr PairTab make_tab() {
    PairTab t{};
    int i = 0;
    for (int d = 0; d < 15; ++d)
        for (int p = d + 1; p < 16; ++p) { t.d[i] = d; t.p[i] = p; ++i; }
    return t;
}
__constant__ constexpr PairTab TAB = make_tab();

// ---------- fused: chunk hist || column records || fp16 row-record repack ---
// gcnt and ctrl must be zeroed before this kernel.
__global__ __launch_bounds__(256) void fused_k(
    const float* __restrict__ z_cols, const float* __restrict__ gamma_cols,
    const float* __restrict__ L, const float* __restrict__ col_times,
    const int* __restrict__ col_idx_list, float* __restrict__ rec,
    const float* __restrict__ z_rows, _Float16* __restrict__ zh,
    const int* __restrict__ mc, int* __restrict__ gcnt)
{
    const int tid = threadIdx.x;
    if (blockIdx.x < HIST_BLKS) {
        __shared__ int h[COLN];
        const int b = blockIdx.x;
        for (int i = tid; i < COLN; i += 256) h[i] = 0;
        __syncthreads();
        const int lo = b * CHUNK, hi = min(lo + CHUNK, EN);
        for (int e = lo + tid; e < hi; e += 256)
            atomicAdd(&h[mc[e]], 1);
        __syncthreads();
        for (int i = tid; i < COLN; i += 256) {
            int v = h[i];
            if (v) atomicAdd(&gcnt[i], v);
        }
    } else if (blockIdx.x < HIST_BLKS + PRE_BLKS) {
        __shared__ float Lsh[DIM][DIM];
        __shared__ float Gsh[DIM][DIM];
        __shared__ float zc[DIM];
        __shared__ float g1[DIM];
        const int c = blockIdx.x - HIST_BLKS;
        const int cidx = col_idx_list[c];

        Lsh[tid >> 4][tid & 15] = L[(size_t)cidx * 256 + tid];
        if (tid < DIM) zc[tid] = z_cols[(size_t)c * DIM + tid];
        __syncthreads();

        const int d = tid >> 4, dp = tid & 15;
        float g = 0.0f;
        #pragma unroll
        for (int k = 0; k < DIM; ++k) g = fmaf(Lsh[d][k], Lsh[dp][k], g);
        Gsh[d][dp] = g;
        __syncthreads();

        if (tid < DIM) {
            float s = 0.0f;
            #pragma unroll
            for (int j = 0; j < DIM; ++j) s = fmaf(Gsh[tid][j], zc[j], s);
            g1[tid] = s;
        }
        __syncthreads();

        float* r = rec + (size_t)c * RECLEN;
        if (tid == 0) {
            float t = col_times[c];
            r[0] = 1.0f;
            r[1] = t;
            r[2] = 0.5f * t * t;
            r[3] = (t * t * t) * (1.0f / 6.0f);
            float g0 = 0.0f;
            #pragma unroll
            for (int j = 0; j < DIM; ++j) g0 = fmaf(g1[j], zc[j], g0);
            r[156] = g0;
            r[157] = gamma_cols[c];
            r[158] = 0.0f;
            r[159] = 0.0f;
        }
        if (tid < DIM) {
            r[4 + tid]   = Gsh[tid][tid];
            r[140 + tid] = 2.0f * g1[tid];
        }
        if (tid < 120) {
            r[20 + tid] = 2.0f * Gsh[TAB.d[tid]][TAB.p[tid]];
        }
    } else {
        // repack z_rows [4][ROWN][16] f32 -> zh [ROWN][64] fp16 (128 B/row)
        const int g = (blockIdx.x - HIST_BLKS - PRE_BLKS) * 4096 + tid * 16;
        if (g < ROWN * 64) {
            const int row = g >> 6;
            const int v = (g & 63) >> 4;
            const float* src = z_rows + (size_t)v * (ROWN * DIM) + (size_t)row * DIM;
            halfv8 o0, o1;
            #pragma unroll
            for (int j = 0; j < 8; ++j) o0[j] = (_Float16)src[j];
            #pragma unroll
            for (int j = 0; j < 8; ++j) o1[j] = (_Float16)src[8 + j];
            halfv8* dst = (halfv8*)(zh + g);
            dst[0] = o0;
            dst[1] = o1;
        }
    }
}

// ---------- single-block scan: counts -> 64-aligned bucket bases ------------
__global__ __launch_bounds__(256) void scan_k(int* __restrict__ gc,
                                              Ctrl* __restrict__ ctrl)
{
    __shared__ int tot[COLN];
    __shared__ int sums[256];
    const int tid = threadIdx.x;
    #pragma unroll
    for (int i = 0; i < 16; ++i) {
        int c = i * 256 + tid;
        tot[c] = (gc[c] + 63) & ~63;          // pad each bucket to 64
    }
    __syncthreads();
    int s = 0;
    #pragma unroll
    for (int i = 0; i < 16; ++i) s += tot[tid * 16 + i];
    sums[tid] = s;
    __syncthreads();
    for (int off = 1; off < 256; off <<= 1) {
        int v = (tid >= off) ? sums[tid - off] : 0;
        __syncthreads();
        sums[tid] += v;
        __syncthreads();
    }
    int run = (tid == 0) ? 0 : sums[tid - 1];
    #pragma unroll
    for (int i = 0; i < 16; ++i) {
        int c = tid * 16 + i;
        int v = tot[c];
        gc[c] = run;          // padded exclusive base -> global cursor
        run += v;
    }
    if (tid == 255) ctrl->pk_len = run;       // total padded length
}

// ---------- scatter: per-block LDS hist -> reserve ranges -> place ----------
__global__ __launch_bounds__(512) void scatter_k(
    const int* __restrict__ mr, const int* __restrict__ mc,
    const int* __restrict__ yy, int* __restrict__ gcur,
    int* __restrict__ packed)
{
    __shared__ int lh[COLN];
    for (int i = threadIdx.x; i < COLN; i += 512) lh[i] = 0;
    __syncthreads();
    const int b = blockIdx.x;
    const int lo = b * CHUNK, hi = min(lo + CHUNK, EN);
    for (int e = lo + threadIdx.x; e < hi; e += 512)
        atomicAdd(&lh[mc[e]], 1);
    __syncthreads();
    for (int i = threadIdx.x; i < COLN; i += 512) {
        int cnt = lh[i];
        if (cnt) lh[i] = atomicAdd(&gcur[i], cnt);
    }
    __syncthreads();
    for (int e = lo + threadIdx.x; e < hi; e += 512) {
        int c = mc[e];
        int pos = atomicAdd(&lh[c], 1);            // LDS cursor
        packed[pos] = mr[e] | (yy[e] << 14) | (c << 17);  // 14+3+12 bits
    }
}

// log( Phi(hi) - Phi(lo) ), cancellation-free, branch-light, always finite.
__device__ __forceinline__ float log_cdf_diff_f(float hi, float lo) {
    const float r = 0.70710678118654752440f;
    if (hi + lo < 0.0f) { float t = hi; hi = -lo; lo = -t; }
    float d = erfcf(lo * r) - erfcf(hi * r);
    return logf(0.5f * fmaxf(d, 1e-37f));
}

// ---------- flat edge kernel: 2 slots/thread/iter, fully predicated ---------
// Sentinel slots (yv==0, incl. e>=n) compute garbage that is masked out --
// no divergent `continue` (it blocked pipelining; R12's VGPR=32 collapse).
__global__ __launch_bounds__(256) void edge_flat(
    const _Float16* __restrict__ zh, const float* __restrict__ gamma_rows,
    const float4* __restrict__ rec4, const float* __restrict__ b,
    const float* __restrict__ sigma, const int* __restrict__ packed,
    Ctrl* __restrict__ ctrl, float* __restrict__ out)
{
    __shared__ float th[6];
    __shared__ double wave_sums[4];
    if (threadIdx.x == 0) { th[0] = -100000.0f; th[5] = 100000.0f; }
    if (threadIdx.x < 4)  th[1 + threadIdx.x] = b[threadIdx.x];
    const float inv_s = 1.0f / sigma[0];
    const int n = ctrl->pk_len;
    __syncthreads();

    double acc = 0.0;
    const int GS = EDGE_BLKS * 256;
    for (int e = blockIdx.x * blockDim.x + threadIdx.x; e < n; e += 2 * GS) {
        const int e2 = e + GS;
        const int p1 = packed[e];
        const int p2 = (e2 < n) ? packed[e2] : 0;

        const int col1 = __builtin_amdgcn_readfirstlane((int)(((unsigned)p1) >> 17));
        const int col2 = __builtin_amdgcn_readfirstlane((int)(((unsigned)p2) >> 17));
        const float4* __restrict__ rpA = rec4 + (size_t)col1 * 40;  // scalar
        const float4* __restrict__ rpB = rec4 + (size_t)col2 * 40;  // scalar
        const int row1 = p1 & 0x3FFF, yv1 = (p1 >> 14) & 7;
        const int row2 = p2 & 0x3FFF, yv2 = (p2 >> 14) & 7;

        // ---- issue all 16 z-loads (two 128B fp16 row records) up front ----
        const float4* zrA = (const float4*)(zh + ((size_t)row1 << 6));
        const float4* zrB = (const float4*)(zh + ((size_t)row2 << 6));
        F4H8 a0, a1, a2, a3, a4, a5, a6, a7;
        F4H8 c0, c1, c2, c3, c4, c5, c6, c7;
        a0.f = zrA[0]; a1.f = zrA[1]; a2.f = zrA[2]; a3.f = zrA[3];
        a4.f = zrA[4]; a5.f = zrA[5]; a6.f = zrA[6]; a7.f = zrA[7];
        c0.f = zrB[0]; c1.f = zrB[1]; c2.f = zrB[2]; c3.f = zrB[3];
        c4.f = zrB[4]; c5.f = zrB[5]; c6.f = zrB[6]; c7.f = zrB[7];
        const float gaA = gamma_rows[row1];
        const float gaB = gamma_rows[row2];

        float lf1, lf2;
        // ================= edge 1 =================
        {
            float4 t0 = rpA[0];
            halfv8 t1v = splat8((_Float16)t0.y);
            halfv8 t2v = splat8((_Float16)t0.z);
            halfv8 t3v = splat8((_Float16)t0.w);
            halfv8 za = a0.h + t1v * a2.h + t2v * a4.h + t3v * a6.h;
            halfv8 zb = a1.h + t1v * a3.h + t2v * a5.h + t3v * a7.h;
            float z[DIM];
            #pragma unroll
            for (int j = 0; j < 8; ++j) { z[j] = (float)za[j]; z[8+j] = (float)zb[j]; }

            float qd = 0.0f;
            #pragma unroll
            for (int q = 0; q < 4; ++q) {
                float4 a = rpA[1 + q];
                qd = fmaf(a.x, z[4*q+0]*z[4*q+0], qd);
                qd = fmaf(a.y, z[4*q+1]*z[4*q+1], qd);
                qd = fmaf(a.z, z[4*q+2]*z[4*q+2], qd);
                qd = fmaf(a.w, z[4*q+3]*z[4*q+3], qd);
            }
            float qc = 0.0f;
            #pragma unroll
            for (int q = 0; q < 30; ++q) {
                float4 bv = rpA[5 + q];
                qc = fmaf(bv.x, z[TAB.d[4*q+0]]*z[TAB.p[4*q+0]], qc);
                qc = fmaf(bv.y, z[TAB.d[4*q+1]]*z[TAB.p[4*q+1]], qc);
                qc = fmaf(bv.z, z[TAB.d[4*q+2]]*z[TAB.p[4*q+2]], qc);
                qc = fmaf(bv.w, z[TAB.d[4*q+3]]*z[TAB.p[4*q+3]], qc);
            }
            float qh = 0.0f;
            #pragma unroll
            for (int q = 0; q < 4; ++q) {
                float4 hv = rpA[35 + q];
                qh = fmaf(hv.x, z[4*q+0], qh);
                qh = fmaf(hv.y, z[4*q+1], qh);
                qh = fmaf(hv.z, z[4*q+2], qh);
                qh = fmaf(hv.w, z[4*q+3], qh);
            }
            float4 tail = rpA[39];
            float dist = sqrtf(fmaxf(qd + qc - qh + tail.x, 0.0f));
            float f = gaA + tail.y - dist;
            int yc = max(yv1, 1);
            lf1 = log_cdf_diff_f((th[yc] - f) * inv_s, (th[yc - 1] - f) * inv_s);
            lf1 = (yv1 == 0) ? 0.0f : lf1;
        }
        // ================= edge 2 =================
        {
            float4 t0 = rpB[0];
            halfv8 t1v = splat8((_Float16)t0.y);
            halfv8 t2v = splat8((_Float16)t0.z);
            halfv8 t3v = splat8((_Float16)t0.w);
            halfv8 za = c0.h + t1v * c2.h + t2v * c4.h + t3v * c6.h;
            halfv8 zb = c1.h + t1v * c3.h + t2v * c5.h + t3v * c7.h;
            float z[DIM];
            #pragma unroll
            for (int j = 0; j < 8; ++j) { z[j] = (float)za[j]; z[8+j] = (float)zb[j]; }

            float qd = 0.0f;
            #pragma unroll
            for (int q = 0; q < 4; ++q) {
                float4 a = rpB[1 + q];
                qd = fmaf(a.x, z[4*q+0]*z[4*q+0], qd);
                qd = fmaf(a.y, z[4*q+1]*z[4*q+1], qd);
                qd = fmaf(a.z, z[4*q+2]*z[4*q+2], qd);
                qd = fmaf(a.w, z[4*q+3]*z[4*q+3], qd);
            }
            float qc = 0.0f;
            #pragma unroll
            for (int q = 0; q < 30; ++q) {
                float4 bv = rpB[5 + q];
                qc = fmaf(bv.x, z[TAB.d[4*q+0]]*z[TAB.p[4*q+0]], qc);
                qc = fmaf(bv.y, z[TAB.d[4*q+1]]*z[TAB.p[4*q+1]], qc);
                qc = fmaf(bv.z, z[TAB.d[4*q+2]]*z[TAB.p[4*q+2]], qc);
                qc = fmaf(bv.w, z[TAB.d[4*q+3]]*z[TAB.p[4*q+3]], qc);
            }
            float qh = 0.0f;
            #pragma unroll
            for (int q = 0; q < 4; ++q) {
                float4 hv = rpB[35 + q];
                qh = fmaf(hv.x, z[4*q+0], qh);
                qh = fmaf(hv.y, z[4*q+1], qh);
                qh = fmaf(hv.z, z[4*q+2], qh);
                qh = fmaf(hv.w, z[4*q+3], qh);
            }
            float4 tail = rpB[39];
            float dist = sqrtf(fmaxf(qd + qc - qh + tail.x, 0.0f));
            float f = gaB + tail.y - dist;
            int yc = max(yv2, 1);
            lf2 = log_cdf_diff_f((th[yc] - f) * inv_s, (th[yc - 1] - f) * inv_s);
            lf2 = (yv2 == 0) ? 0.0f : lf2;
        }
        acc += (double)(lf1 + lf2);
    }

    #pragma unroll
    for (int off = 32; off > 0; off >>= 1) acc += __shfl_down(acc, off, 64);
    const int lane = threadIdx.x & 63;
    const int wid  = threadIdx.x >> 6;
    if (lane == 0) wave_sums[wid] = acc;
    __syncthreads();
    if (threadIdx.x == 0) {
        double t = wave_sums[0] + wave_sums[1] + wave_sums[2] + wave_sums[3];
        atomicAdd(&ctrl->acc, t);        // native f64 atomic (NOT a CAS loop)
        __threadfence();
        int done = atomicAdd(&ctrl->blkcnt, 1);
        if (done == (int)gridDim.x - 1) {
            __threadfence();
            double totald = atomicAdd(&ctrl->acc, 0.0);  // device-scope read
            out[0] = -(float)totald;
        }
    }
}

extern "C" void kernel_launch(void* const* d_in, const int* in_sizes, int n_in,
                              void* d_out, int out_size, void* d_ws, size_t ws_size,
                              hipStream_t stream) {
    const float* z_rows       = (const float*)d_in[0];
    const float* z_cols       = (const float*)d_in[1];
    const float* gamma_rows   = (const float*)d_in[2];
    const float* gamma_cols   = (const float*)d_in[3];
    const float* L            = (const float*)d_in[4];
    const float* b            = (const float*)d_in[5];
    const float* sigma        = (const float*)d_in[6];
    const float* col_times    = (const float*)d_in[7];
    const int*   mat_rows     = (const int*)d_in[8];
    const int*   mat_cols     = (const int*)d_in[9];
    const int*   y            = (const int*)d_in[10];
    const int*   col_idx_list = (const int*)d_in[11];

    // workspace layout (16B-aligned); total ~8.97 MB
    char* ws = (char*)d_ws;
    float*     rec  = (float*)ws;                      // 2,621,440 B
    int*       gcur = (int*)(ws + 2621440);            //    16,384 B
    Ctrl*      ctrl = (Ctrl*)(ws + 2637824);           //        16 B
    _Float16*  zh   = (_Float16*)(ws + 2637840);       // 1,280,000 B
    int*       pk   = (int*)(ws + 3917840);            // 5,046,272 B

    hipMemsetAsync(gcur, 0, 16384 + 16, stream);             // counts + ctrl
    hipMemsetAsync(pk, 0, (size_t)PK_CAP * 4, stream);       // yv==0 sentinels
    fused_k<<<HIST_BLKS + PRE_BLKS + RPK_BLKS, 256, 0, stream>>>(
        z_cols, gamma_cols, L, col_times, col_idx_list, rec,
        z_rows, zh, mat_cols, gcur);
    scan_k<<<1, 256, 0, stream>>>(gcur, ctrl);
    scatter_k<<<NB, 512, 0, stream>>>(mat_rows, mat_cols, y, gcur, pk);
    edge_flat<<<EDGE_BLKS, 256, 0, stream>>>(
        zh, gamma_rows, (const float4*)rec, b, sigma, pk, ctrl,
        (float*)d_out);
}